// Round 1
// 1306.252 us; speedup vs baseline: 1.1689x; 1.1689x over previous
//
#include <hip/hip_runtime.h>
#include <hip/hip_bf16.h>
#include <stdint.h>

#define NN   100000
#define EE   3200000
#define HD   128

typedef short v8s __attribute__((ext_vector_type(8)));
typedef float v4f __attribute__((ext_vector_type(4)));

__device__ __forceinline__ unsigned short f2bf(float f){
  union { float f; unsigned int i; } v; v.f = f;
  unsigned int r = v.i + 0x7fffu + ((v.i >> 16) & 1u);
  return (unsigned short)(r >> 16);
}
__device__ __forceinline__ uint4 pack8(float4 lo, float4 hi){
  uint4 r;
  r.x = (unsigned)f2bf(lo.x) | ((unsigned)f2bf(lo.y) << 16);
  r.y = (unsigned)f2bf(lo.z) | ((unsigned)f2bf(lo.w) << 16);
  r.z = (unsigned)f2bf(hi.x) | ((unsigned)f2bf(hi.y) << 16);
  r.w = (unsigned)f2bf(hi.z) | ((unsigned)f2bf(hi.w) << 16);
  return r;
}

// ---------------- graph build ----------------
__global__ void k_zero(int* p, int n){
  int i = blockIdx.x*blockDim.x + threadIdx.x; if (i < n) p[i] = 0;
}
// pass 1: histogram AND per-edge rank within its destination bucket.
// This is the only atomic pass in the whole CSR build (was 2x 3.2M atomics).
__global__ void k_histrank(const int* __restrict__ dst, int* __restrict__ cnt,
                           int* __restrict__ rank, int e){
  int i = blockIdx.x*blockDim.x + threadIdx.x;
  if (i < e) rank[i] = atomicAdd(&cnt[dst[i]], 1);
}
__global__ __launch_bounds__(1024)
void k_scan1(const int* __restrict__ cnt, int* __restrict__ offs, int* __restrict__ blksum, int n){
  __shared__ int lds[1024];
  int t = threadIdx.x; int i = blockIdx.x*1024 + t;
  int v = (i < n) ? cnt[i] : 0;
  lds[t] = v; __syncthreads();
  for (int s = 1; s < 1024; s <<= 1){
    int add = (t >= s) ? lds[t-s] : 0;
    __syncthreads();
    lds[t] += add;
    __syncthreads();
  }
  if (i < n) offs[i] = lds[t] - v;           // exclusive
  if (t == 1023) blksum[blockIdx.x] = lds[1023];
}
// parallel one-block scan of the (<=128) block sums — was a single-thread
// dependent global RMW chain (~98 serial L2 round-trips).
__global__ __launch_bounds__(128)
void k_scan2(int* __restrict__ blksum, int nb){
  __shared__ int lds[128];
  int t = threadIdx.x;
  int v = (t < nb) ? blksum[t] : 0;
  lds[t] = v; __syncthreads();
  for (int s = 1; s < 128; s <<= 1){
    int a = (t >= s) ? lds[t-s] : 0;
    __syncthreads();
    lds[t] += a;
    __syncthreads();
  }
  if (t < nb) blksum[t] = lds[t] - v;        // exclusive
}
__global__ __launch_bounds__(1024)
void k_scan3(int* __restrict__ offs, const int* __restrict__ blksum, int n){
  int i = blockIdx.x*1024 + threadIdx.x;
  if (i < n) offs[i] += blksum[blockIdx.x];
}
// pass 2: atomic-free placement using the precomputed rank.
__global__ void k_place(const int* __restrict__ src, const int* __restrict__ dst,
                        const int* __restrict__ offs, const int* __restrict__ rank,
                        int* __restrict__ ssrc, int e){
  int i = blockIdx.x*blockDim.x + threadIdx.x;
  if (i < e) ssrc[offs[dst[i]] + rank[i]] = src[i];
}

// -------- bf16-MFMA GEMM with fp32 inputs: C_bf16[M,128] = relu?(A@B^T + bias) --------
// A segments may be fp32 (inputs) or bf16 (our workspace); B (weights) always fp32.
// fp32 data is rounded to bf16 during LDS staging.
__device__ __forceinline__ void gemm_issue(int t, int T0, int M, int gm, int r0, int c8,
    const void* __restrict__ A0, int lda0, int a0f32,
    const void* __restrict__ A1, int lda1, int a1f32,
    const float* __restrict__ B0, int ldb0,
    const float* __restrict__ B1, int ldb1,
    uint4* as, uint4* bs)
{
  const void* Ag; const float* Bg; int la, lb, ko, af32;
  if (t < T0){ Ag = A0; la = lda0; af32 = a0f32; Bg = B0; lb = ldb0; ko = t*64; }
  else       { Ag = A1; la = lda1; af32 = a1f32; Bg = B1; lb = ldb1; ko = (t-T0)*64; }
#pragma unroll
  for (int p = 0; p < 4; p++){
    int row  = r0 + p*32;
    int grow = gm + row;
    if (grow < M){
      if (af32){
        const float* ap = (const float*)Ag + (size_t)grow*la + ko + c8;
        as[p] = pack8(*(const float4*)ap, *(const float4*)(ap + 4));
      } else {
        as[p] = *(const uint4*)((const unsigned short*)Ag + (size_t)grow*la + ko + c8);
      }
    } else {
      as[p] = make_uint4(0u,0u,0u,0u);
    }
    const float* bp = Bg + (size_t)row*lb + ko + c8;
    bs[p] = pack8(*(const float4*)bp, *(const float4*)(bp + 4));
  }
}

__global__ __launch_bounds__(256)
void k_gemm(int M,
            const void* __restrict__ A0, int lda0, int K0, int a0f32,
            const void* __restrict__ A1, int lda1, int K1, int a1f32,
            const float* __restrict__ B0, int ldb0,
            const float* __restrict__ B1, int ldb1,
            const float* __restrict__ bias, int do_relu,
            unsigned short* __restrict__ C, int ldc)
{
  __shared__ unsigned short Abuf[128*72];   // BK=64 bf16, pad 8
  __shared__ unsigned short Bbuf[128*72];
  const int tid = threadIdx.x;
  const int gm  = blockIdx.x * 128;
  const int T0  = K0 >> 6;
  const int T   = (K0 + K1) >> 6;

  const int r0 = tid >> 3;          // 0..31
  const int c8 = (tid & 7) * 8;     // 0..56

  const int lane = tid & 63;
  const int w  = tid >> 6;
  const int wm = w >> 1, wn = w & 1;
  const int l15 = lane & 15, q = lane >> 4;

  v4f acc[4][4];
#pragma unroll
  for (int mi = 0; mi < 4; mi++)
#pragma unroll
    for (int ni = 0; ni < 4; ni++){ v4f z = {0.f,0.f,0.f,0.f}; acc[mi][ni] = z; }

  uint4 aS[4], bS[4];
  gemm_issue(0, T0, M, gm, r0, c8, A0, lda0, a0f32, A1, lda1, a1f32,
             B0, ldb0, B1, ldb1, aS, bS);

  for (int t = 0; t < T; ++t){
#pragma unroll
    for (int p = 0; p < 4; p++){
      int row = r0 + p*32;
      *(uint4*)(Abuf + row*72 + c8) = aS[p];
      *(uint4*)(Bbuf + row*72 + c8) = bS[p];
    }
    __syncthreads();
    if (t + 1 < T)
      gemm_issue(t+1, T0, M, gm, r0, c8, A0, lda0, a0f32, A1, lda1, a1f32,
                 B0, ldb0, B1, ldb1, aS, bS);
#pragma unroll
    for (int kk = 0; kk < 64; kk += 32){
      v8s af[4], bf[4];
#pragma unroll
      for (int mi = 0; mi < 4; mi++)
        af[mi] = *(const v8s*)(Abuf + (wm*64 + mi*16 + l15)*72 + kk + q*8);
#pragma unroll
      for (int ni = 0; ni < 4; ni++)
        bf[ni] = *(const v8s*)(Bbuf + (wn*64 + ni*16 + l15)*72 + kk + q*8);
#pragma unroll
      for (int mi = 0; mi < 4; mi++)
#pragma unroll
        for (int ni = 0; ni < 4; ni++)
          acc[mi][ni] = __builtin_amdgcn_mfma_f32_16x16x32_bf16(af[mi], bf[ni], acc[mi][ni], 0, 0, 0);
    }
    __syncthreads();
  }

  // epilogue: D col = lane&15, row = (lane>>4)*4 + reg (m89-verified mapping)
#pragma unroll
  for (int ni = 0; ni < 4; ni++){
    int n = wn*64 + ni*16 + l15;
    float bv = bias ? bias[n] : 0.0f;
#pragma unroll
    for (int mi = 0; mi < 4; mi++){
#pragma unroll
      for (int r = 0; r < 4; r++){
        int row = gm + wm*64 + mi*16 + q*4 + r;
        if (row < M){
          float v = acc[mi][ni][r] + bv;
          if (do_relu) v = v > 0.f ? v : 0.f;
          C[(size_t)row*ldc + n] = f2bf(v);
        }
      }
    }
  }
}

// ---------------- layer-1 aggregate + finish + fused C=4 projections ----------------
// one wave per node: x2 = relu(mean(y1[nbrs]) + z1); y2 = x2@Wl2^T; r2 = x2@Wr2^T + bl2
__global__ __launch_bounds__(256)
void k_agg1(const int* __restrict__ offs, const int* __restrict__ cnt,
            const int* __restrict__ ssrc,
            const unsigned short* __restrict__ y1,
            const unsigned short* __restrict__ z1,
            const float* __restrict__ Wl2,
            const float* __restrict__ Wr2,
            const float* __restrict__ bl2,
            float* __restrict__ y2, float* __restrict__ r2, int n)
{
  int wid  = (blockIdx.x * blockDim.x + threadIdx.x) >> 6;
  int lane = threadIdx.x & 63;
  if (wid >= n) return;
  int start = offs[wid];
  int deg   = cnt[wid];
  const unsigned int* y1u = (const unsigned int*)y1;  // 2 bf16 per uint; lane covers feats 2l, 2l+1
  float a0 = 0.f, a1 = 0.f;
  for (int base = 0; base < deg; base += 64){
    int idx = base + lane;
    int sl  = (idx < deg) ? ssrc[start + idx] : 0;
    int m   = deg - base; if (m > 64) m = 64;
    for (int t = 0; t < m; ++t){
      int s = __shfl(sl, t, 64);
      unsigned int u = y1u[(size_t)s*64 + lane];
      union {unsigned int i; float f;} lo, hi;
      lo.i = u << 16; hi.i = u & 0xffff0000u;
      a0 += lo.f; a1 += hi.f;
    }
  }
  float scale = 1.0f / (float)(deg > 0 ? deg : 1);
  unsigned int zu = ((const unsigned int*)z1)[(size_t)wid*64 + lane];
  union {unsigned int i; float f;} zl, zh;
  zl.i = zu << 16; zh.i = zu & 0xffff0000u;
  float x0 = a0*scale + zl.f; x0 = x0 > 0.f ? x0 : 0.f;
  float x1 = a1*scale + zh.f; x1 = x1 > 0.f ? x1 : 0.f;

  float pl[4], pr[4];
#pragma unroll
  for (int c = 0; c < 4; c++){
    float2 wl = ((const float2*)Wl2)[c*64 + lane];   // feats 2l, 2l+1 of row c
    float2 wr = ((const float2*)Wr2)[c*64 + lane];
    pl[c] = x0*wl.x + x1*wl.y;
    pr[c] = x0*wr.x + x1*wr.y;
  }
#pragma unroll
  for (int off = 32; off > 0; off >>= 1){
#pragma unroll
    for (int c = 0; c < 4; c++){
      pl[c] += __shfl_xor(pl[c], off, 64);
      pr[c] += __shfl_xor(pr[c], off, 64);
    }
  }
  if (lane < 4){
    y2[(size_t)wid*4 + lane] = pl[lane];
    r2[(size_t)wid*4 + lane] = pr[lane] + bl2[lane];
  }
}

// ---------------- layer-2 aggregate + fp32 output ----------------
__global__ void k_agg2(const int* __restrict__ offs, const int* __restrict__ cnt,
                       const int* __restrict__ ssrc,
                       const float* __restrict__ y2, const float* __restrict__ r2,
                       float* __restrict__ out, int n)
{
  int i = blockIdx.x * blockDim.x + threadIdx.x;
  if (i >= n) return;
  int start = offs[i], deg = cnt[i];
  float a0 = 0.f, a1 = 0.f, a2 = 0.f, a3 = 0.f;
  for (int e = 0; e < deg; e++){
    int s = ssrc[start + e];
    float4 v = *(const float4*)(y2 + (size_t)s*4);
    a0 += v.x; a1 += v.y; a2 += v.z; a3 += v.w;
  }
  float sc = 1.0f / (float)(deg > 0 ? deg : 1);
  float4 r = *(const float4*)(r2 + (size_t)i*4);
  float4 o;
  o.x = a0*sc + r.x; o.y = a1*sc + r.y; o.z = a2*sc + r.z; o.w = a3*sc + r.w;
  *(float4*)(out + (size_t)i*4) = o;
}

extern "C" void kernel_launch(void* const* d_in, const int* in_sizes, int n_in,
                              void* d_out, int out_size, void* d_ws, size_t ws_size,
                              hipStream_t stream)
{
  (void)in_sizes; (void)n_in; (void)out_size; (void)ws_size;
  const float* clinical = (const float*)d_in[0];
  const float* mel      = (const float*)d_in[1];
  const int*   ei       = (const int*)d_in[2];
  const float* Wm  = (const float*)d_in[3];
  const float* bm  = (const float*)d_in[4];
  const float* Wc  = (const float*)d_in[5];
  const float* bc  = (const float*)d_in[6];
  const float* Wl1 = (const float*)d_in[7];
  const float* bl1 = (const float*)d_in[8];
  const float* Wr1 = (const float*)d_in[9];
  const float* Wl2 = (const float*)d_in[10];
  const float* bl2 = (const float*)d_in[11];
  const float* Wr2 = (const float*)d_in[12];
  const int* src = ei;
  const int* dst = ei + EE;

  char* w = (char*)d_ws;
  auto alloc = [&](size_t sz){ void* p = (void*)w; w += (sz + 255) & ~(size_t)255; return p; };
  unsigned short* mel_h = (unsigned short*)alloc((size_t)NN*HD*2);  // reused as y1 after GEMM2
  unsigned short* x     = (unsigned short*)alloc((size_t)NN*HD*2);
  unsigned short* z1    = (unsigned short*)alloc((size_t)NN*HD*2);
  int*   ssrc   = (int*)alloc((size_t)EE*4);
  int*   rank   = (int*)alloc((size_t)EE*4);
  int*   cnt    = (int*)alloc((size_t)NN*4);
  int*   offs   = (int*)alloc((size_t)NN*4);
  int*   blksum = (int*)alloc(4096);
  float* y2     = (float*)alloc((size_t)NN*4*4);
  float* r2     = (float*)alloc((size_t)NN*4*4);

  // --- CSR build: single atomic pass (hist+rank), scan, atomic-free place ---
  k_zero<<<(NN+255)/256, 256, 0, stream>>>(cnt, NN);
  k_histrank<<<(EE+255)/256, 256, 0, stream>>>(dst, cnt, rank, EE);
  int nblk = (NN + 1023) / 1024;  // 98
  k_scan1<<<nblk, 1024, 0, stream>>>(cnt, offs, blksum, NN);
  k_scan2<<<1, 128, 0, stream>>>(blksum, nblk);
  k_scan3<<<nblk, 1024, 0, stream>>>(offs, blksum, NN);
  k_place<<<(EE+255)/256, 256, 0, stream>>>(src, dst, offs, rank, ssrc, EE);

  int gmb = (NN + 127) / 128;     // 782 row tiles
  // mel_h = relu(mel @ Wm^T + bm)          (A fp32, B fp32)
  k_gemm<<<gmb, 256, 0, stream>>>(NN, mel, 1280, 1280, 1, nullptr, 0, 0, 0,
                                  Wm, 1280, nullptr, 0, bm, 1, mel_h, HD);
  // x = relu([clinical | mel_h] @ Wc^T + bc)   (seg0 fp32 K=64, seg1 bf16 K=128)
  k_gemm<<<gmb, 256, 0, stream>>>(NN, clinical, 64, 64, 1, mel_h, HD, HD, 0,
                                  Wc, 192, Wc + 64, 192, bc, 1, x, HD);
  // y1 = x @ Wl1^T   (into mel_h buffer — mel_h dead after GEMM2)
  unsigned short* y1 = mel_h;
  k_gemm<<<gmb, 256, 0, stream>>>(NN, x, HD, HD, 0, nullptr, 0, 0, 0,
                                  Wl1, HD, nullptr, 0, nullptr, 0, y1, HD);
  // z1 = x @ Wr1^T + bl1
  k_gemm<<<gmb, 256, 0, stream>>>(NN, x, HD, HD, 0, nullptr, 0, 0, 0,
                                  Wr1, HD, nullptr, 0, bl1, 0, z1, HD);

  // layer-1 aggregate + relu + fused layer-2 projections
  k_agg1<<<(NN+3)/4, 256, 0, stream>>>(offs, cnt, ssrc, y1, z1, Wl2, Wr2, bl2, y2, r2, NN);
  // layer-2 aggregate + fp32 output
  k_agg2<<<(NN+255)/256, 256, 0, stream>>>(offs, cnt, ssrc, y2, r2, (float*)d_out, NN);
}

// Round 2
// 1241.455 us; speedup vs baseline: 1.2300x; 1.0522x over previous
//
#include <hip/hip_runtime.h>
#include <hip/hip_bf16.h>
#include <stdint.h>

#define NN   100000
#define EE   3200000
#define HD   128

typedef short v8s __attribute__((ext_vector_type(8)));
typedef float v4f __attribute__((ext_vector_type(4)));

__device__ __forceinline__ unsigned short f2bf(float f){
  union { float f; unsigned int i; } v; v.f = f;
  unsigned int r = v.i + 0x7fffu + ((v.i >> 16) & 1u);
  return (unsigned short)(r >> 16);
}
__device__ __forceinline__ uint4 pack8(float4 lo, float4 hi){
  uint4 r;
  r.x = (unsigned)f2bf(lo.x) | ((unsigned)f2bf(lo.y) << 16);
  r.y = (unsigned)f2bf(lo.z) | ((unsigned)f2bf(lo.w) << 16);
  r.z = (unsigned)f2bf(hi.x) | ((unsigned)f2bf(hi.y) << 16);
  r.w = (unsigned)f2bf(hi.z) | ((unsigned)f2bf(hi.w) << 16);
  return r;
}
// accumulate 8 bf16 features packed in a uint4 into float a[8]
__device__ __forceinline__ void acc8(float* a, uint4 u){
  union {unsigned int i; float f;} t;
  t.i = u.x << 16;         a[0] += t.f;
  t.i = u.x & 0xffff0000u; a[1] += t.f;
  t.i = u.y << 16;         a[2] += t.f;
  t.i = u.y & 0xffff0000u; a[3] += t.f;
  t.i = u.z << 16;         a[4] += t.f;
  t.i = u.z & 0xffff0000u; a[5] += t.f;
  t.i = u.w << 16;         a[6] += t.f;
  t.i = u.w & 0xffff0000u; a[7] += t.f;
}

// ---------------- graph build ----------------
__global__ void k_zero(int* p, int n){
  int i = blockIdx.x*blockDim.x + threadIdx.x; if (i < n) p[i] = 0;
}
// pass 1: histogram AND per-edge rank within its destination bucket.
__global__ void k_histrank(const int* __restrict__ dst, int* __restrict__ cnt,
                           int* __restrict__ rank, int e){
  int i = blockIdx.x*blockDim.x + threadIdx.x;
  if (i < e) rank[i] = atomicAdd(&cnt[dst[i]], 1);
}
__global__ __launch_bounds__(1024)
void k_scan1(const int* __restrict__ cnt, int* __restrict__ offs, int* __restrict__ blksum, int n){
  __shared__ int lds[1024];
  int t = threadIdx.x; int i = blockIdx.x*1024 + t;
  int v = (i < n) ? cnt[i] : 0;
  lds[t] = v; __syncthreads();
  for (int s = 1; s < 1024; s <<= 1){
    int add = (t >= s) ? lds[t-s] : 0;
    __syncthreads();
    lds[t] += add;
    __syncthreads();
  }
  if (i < n) offs[i] = lds[t] - v;           // exclusive
  if (t == 1023) blksum[blockIdx.x] = lds[1023];
}
__global__ __launch_bounds__(128)
void k_scan2(int* __restrict__ blksum, int nb){
  __shared__ int lds[128];
  int t = threadIdx.x;
  int v = (t < nb) ? blksum[t] : 0;
  lds[t] = v; __syncthreads();
  for (int s = 1; s < 128; s <<= 1){
    int a = (t >= s) ? lds[t-s] : 0;
    __syncthreads();
    lds[t] += a;
    __syncthreads();
  }
  if (t < nb) blksum[t] = lds[t] - v;        // exclusive
}
__global__ __launch_bounds__(1024)
void k_scan3(int* __restrict__ offs, const int* __restrict__ blksum, int n){
  int i = blockIdx.x*1024 + threadIdx.x;
  if (i < n) offs[i] += blksum[blockIdx.x];
}
// pass 2: atomic-free placement using the precomputed rank.
__global__ void k_place(const int* __restrict__ src, const int* __restrict__ dst,
                        const int* __restrict__ offs, const int* __restrict__ rank,
                        int* __restrict__ ssrc, int e){
  int i = blockIdx.x*blockDim.x + threadIdx.x;
  if (i < e) ssrc[offs[dst[i]] + rank[i]] = src[i];
}

// -------- bf16-MFMA GEMM with fp32 inputs: C_bf16[M,128] = relu?(A@B^T + bias) --------
__device__ __forceinline__ void gemm_issue(int t, int T0, int M, int gm, int r0, int c8,
    const void* __restrict__ A0, int lda0, int a0f32,
    const void* __restrict__ A1, int lda1, int a1f32,
    const float* __restrict__ B0, int ldb0,
    const float* __restrict__ B1, int ldb1,
    uint4* as, uint4* bs)
{
  const void* Ag; const float* Bg; int la, lb, ko, af32;
  if (t < T0){ Ag = A0; la = lda0; af32 = a0f32; Bg = B0; lb = ldb0; ko = t*64; }
  else       { Ag = A1; la = lda1; af32 = a1f32; Bg = B1; lb = ldb1; ko = (t-T0)*64; }
#pragma unroll
  for (int p = 0; p < 4; p++){
    int row  = r0 + p*32;
    int grow = gm + row;
    if (grow < M){
      if (af32){
        const float* ap = (const float*)Ag + (size_t)grow*la + ko + c8;
        as[p] = pack8(*(const float4*)ap, *(const float4*)(ap + 4));
      } else {
        as[p] = *(const uint4*)((const unsigned short*)Ag + (size_t)grow*la + ko + c8);
      }
    } else {
      as[p] = make_uint4(0u,0u,0u,0u);
    }
    const float* bp = Bg + (size_t)row*lb + ko + c8;
    bs[p] = pack8(*(const float4*)bp, *(const float4*)(bp + 4));
  }
}

__global__ __launch_bounds__(256)
void k_gemm(int M,
            const void* __restrict__ A0, int lda0, int K0, int a0f32,
            const void* __restrict__ A1, int lda1, int K1, int a1f32,
            const float* __restrict__ B0, int ldb0,
            const float* __restrict__ B1, int ldb1,
            const float* __restrict__ bias, int do_relu,
            unsigned short* __restrict__ C, int ldc)
{
  __shared__ unsigned short Abuf[128*72];   // BK=64 bf16, pad 8
  __shared__ unsigned short Bbuf[128*72];
  const int tid = threadIdx.x;
  const int gm  = blockIdx.x * 128;
  const int T0  = K0 >> 6;
  const int T   = (K0 + K1) >> 6;

  const int r0 = tid >> 3;          // 0..31
  const int c8 = (tid & 7) * 8;     // 0..56

  const int lane = tid & 63;
  const int w  = tid >> 6;
  const int wm = w >> 1, wn = w & 1;
  const int l15 = lane & 15, q = lane >> 4;

  v4f acc[4][4];
#pragma unroll
  for (int mi = 0; mi < 4; mi++)
#pragma unroll
    for (int ni = 0; ni < 4; ni++){ v4f z = {0.f,0.f,0.f,0.f}; acc[mi][ni] = z; }

  uint4 aS[4], bS[4];
  gemm_issue(0, T0, M, gm, r0, c8, A0, lda0, a0f32, A1, lda1, a1f32,
             B0, ldb0, B1, ldb1, aS, bS);

  for (int t = 0; t < T; ++t){
#pragma unroll
    for (int p = 0; p < 4; p++){
      int row = r0 + p*32;
      *(uint4*)(Abuf + row*72 + c8) = aS[p];
      *(uint4*)(Bbuf + row*72 + c8) = bS[p];
    }
    __syncthreads();
    if (t + 1 < T)
      gemm_issue(t+1, T0, M, gm, r0, c8, A0, lda0, a0f32, A1, lda1, a1f32,
                 B0, ldb0, B1, ldb1, aS, bS);
#pragma unroll
    for (int kk = 0; kk < 64; kk += 32){
      v8s af[4], bf[4];
#pragma unroll
      for (int mi = 0; mi < 4; mi++)
        af[mi] = *(const v8s*)(Abuf + (wm*64 + mi*16 + l15)*72 + kk + q*8);
#pragma unroll
      for (int ni = 0; ni < 4; ni++)
        bf[ni] = *(const v8s*)(Bbuf + (wn*64 + ni*16 + l15)*72 + kk + q*8);
#pragma unroll
      for (int mi = 0; mi < 4; mi++)
#pragma unroll
        for (int ni = 0; ni < 4; ni++)
          acc[mi][ni] = __builtin_amdgcn_mfma_f32_16x16x32_bf16(af[mi], bf[ni], acc[mi][ni], 0, 0, 0);
    }
    __syncthreads();
  }

  // epilogue: D col = lane&15, row = (lane>>4)*4 + reg (m89-verified mapping)
#pragma unroll
  for (int ni = 0; ni < 4; ni++){
    int n = wn*64 + ni*16 + l15;
    float bv = bias ? bias[n] : 0.0f;
#pragma unroll
    for (int mi = 0; mi < 4; mi++){
#pragma unroll
      for (int r = 0; r < 4; r++){
        int row = gm + wm*64 + mi*16 + q*4 + r;
        if (row < M){
          float v = acc[mi][ni][r] + bv;
          if (do_relu) v = v > 0.f ? v : 0.f;
          C[(size_t)row*ldc + n] = f2bf(v);
        }
      }
    }
  }
}

// ---------------- layer-1 aggregate + finish + fused C=4 projections ----------------
// one wave per node. Gather 4 neighbor rows per iteration: 16-lane group g
// handles edge quad-member g; each lane reads uint4 (8 bf16 feats) of its row.
// 2x manual unroll -> 2 outstanding 1KB loads per wave.
__global__ __launch_bounds__(256)
void k_agg1(const int* __restrict__ offs, const int* __restrict__ cnt,
            const int* __restrict__ ssrc,
            const unsigned short* __restrict__ y1,
            const unsigned short* __restrict__ z1,
            const float* __restrict__ Wl2,
            const float* __restrict__ Wr2,
            const float* __restrict__ bl2,
            float* __restrict__ y2, float* __restrict__ r2, int n)
{
  int wid  = (blockIdx.x * blockDim.x + threadIdx.x) >> 6;
  int lane = threadIdx.x & 63;
  if (wid >= n) return;
  int start = offs[wid];
  int deg   = cnt[wid];
  const uint4* y1q = (const uint4*)y1;   // one row = 16 uint4
  const int g = lane >> 4;               // 0..3: edge within quad
  const int c = lane & 15;               // feature chunk: feats 8c..8c+7

  float a[8];
#pragma unroll
  for (int j = 0; j < 8; j++) a[j] = 0.f;

  for (int base = 0; base < deg; base += 64){
    int idx = base + lane;
    int sl  = (idx < deg) ? ssrc[start + idx] : 0;
    int m   = deg - base; if (m > 64) m = 64;
    int quads = (m + 3) >> 2;
    int tq = 0;
    for (; tq + 2 <= quads; tq += 2){
      int e0 = tq*4 + g, e1 = e0 + 4;
      int i0 = e0 < m ? e0 : m-1;
      int i1 = e1 < m ? e1 : m-1;
      int s0 = __shfl(sl, i0, 64);
      int s1 = __shfl(sl, i1, 64);
      uint4 u0 = y1q[(size_t)s0*16 + c];
      uint4 u1 = y1q[(size_t)s1*16 + c];
      if (e0 < m) acc8(a, u0);
      if (e1 < m) acc8(a, u1);
    }
    if (tq < quads){
      int e0 = tq*4 + g;
      int i0 = e0 < m ? e0 : m-1;
      int s0 = __shfl(sl, i0, 64);
      uint4 u0 = y1q[(size_t)s0*16 + c];
      if (e0 < m) acc8(a, u0);
    }
  }
  // combine the 4 edge-groups: after this all lanes of a column-class agree
#pragma unroll
  for (int j = 0; j < 8; j++){
    a[j] += __shfl_xor(a[j], 16, 64);
    a[j] += __shfl_xor(a[j], 32, 64);
  }

  float scale = 1.0f / (float)(deg > 0 ? deg : 1);
  uint4 zu = ((const uint4*)z1)[(size_t)wid*16 + c];
  float x8[8];
  {
    union {unsigned int i; float f;} t;
    t.i = zu.x << 16;         x8[0] = t.f;
    t.i = zu.x & 0xffff0000u; x8[1] = t.f;
    t.i = zu.y << 16;         x8[2] = t.f;
    t.i = zu.y & 0xffff0000u; x8[3] = t.f;
    t.i = zu.z << 16;         x8[4] = t.f;
    t.i = zu.z & 0xffff0000u; x8[5] = t.f;
    t.i = zu.w << 16;         x8[6] = t.f;
    t.i = zu.w & 0xffff0000u; x8[7] = t.f;
  }
#pragma unroll
  for (int j = 0; j < 8; j++){
    float v = a[j]*scale + x8[j];
    x8[j] = v > 0.f ? v : 0.f;
  }

  // fused C=4 projections: each lane dots its 8 feats, reduce over 16 classes
  float pl[4], pr[4];
#pragma unroll
  for (int cc = 0; cc < 4; cc++){
    const float* wl = Wl2 + cc*128 + 8*c;
    const float* wr = Wr2 + cc*128 + 8*c;
    float4 wl0 = *(const float4*)wl, wl1 = *(const float4*)(wl + 4);
    float4 wr0 = *(const float4*)wr, wr1 = *(const float4*)(wr + 4);
    pl[cc] = x8[0]*wl0.x + x8[1]*wl0.y + x8[2]*wl0.z + x8[3]*wl0.w
           + x8[4]*wl1.x + x8[5]*wl1.y + x8[6]*wl1.z + x8[7]*wl1.w;
    pr[cc] = x8[0]*wr0.x + x8[1]*wr0.y + x8[2]*wr0.z + x8[3]*wr0.w
           + x8[4]*wr1.x + x8[5]*wr1.y + x8[6]*wr1.z + x8[7]*wr1.w;
  }
#pragma unroll
  for (int off = 8; off >= 1; off >>= 1){
#pragma unroll
    for (int cc = 0; cc < 4; cc++){
      pl[cc] += __shfl_xor(pl[cc], off, 64);
      pr[cc] += __shfl_xor(pr[cc], off, 64);
    }
  }
  if (lane == 0){
    float4 o; o.x = pl[0]; o.y = pl[1]; o.z = pl[2]; o.w = pl[3];
    *(float4*)(y2 + (size_t)wid*4) = o;
    float4 b = *(const float4*)bl2;
    float4 p; p.x = pr[0]+b.x; p.y = pr[1]+b.y; p.z = pr[2]+b.z; p.w = pr[3]+b.w;
    *(float4*)(r2 + (size_t)wid*4) = p;
  }
}

// ---------------- layer-2 aggregate + fp32 output ----------------
// one wave per node, one edge per lane (16B y2 row per lane), butterfly reduce
__global__ __launch_bounds__(256)
void k_agg2(const int* __restrict__ offs, const int* __restrict__ cnt,
            const int* __restrict__ ssrc,
            const float* __restrict__ y2, const float* __restrict__ r2,
            float* __restrict__ out, int n)
{
  int wid  = (blockIdx.x * blockDim.x + threadIdx.x) >> 6;
  int lane = threadIdx.x & 63;
  if (wid >= n) return;
  int start = offs[wid], deg = cnt[wid];
  float a0 = 0.f, a1 = 0.f, a2 = 0.f, a3 = 0.f;
  for (int base = 0; base < deg; base += 64){
    int idx = base + lane;
    if (idx < deg){
      int s = ssrc[start + idx];
      float4 v = *(const float4*)(y2 + (size_t)s*4);
      a0 += v.x; a1 += v.y; a2 += v.z; a3 += v.w;
    }
  }
#pragma unroll
  for (int off = 32; off >= 1; off >>= 1){
    a0 += __shfl_xor(a0, off, 64);
    a1 += __shfl_xor(a1, off, 64);
    a2 += __shfl_xor(a2, off, 64);
    a3 += __shfl_xor(a3, off, 64);
  }
  if (lane == 0){
    float sc = 1.0f / (float)(deg > 0 ? deg : 1);
    float4 r = *(const float4*)(r2 + (size_t)wid*4);
    float4 o;
    o.x = a0*sc + r.x; o.y = a1*sc + r.y; o.z = a2*sc + r.z; o.w = a3*sc + r.w;
    *(float4*)(out + (size_t)wid*4) = o;
  }
}

extern "C" void kernel_launch(void* const* d_in, const int* in_sizes, int n_in,
                              void* d_out, int out_size, void* d_ws, size_t ws_size,
                              hipStream_t stream)
{
  (void)in_sizes; (void)n_in; (void)out_size; (void)ws_size;
  const float* clinical = (const float*)d_in[0];
  const float* mel      = (const float*)d_in[1];
  const int*   ei       = (const int*)d_in[2];
  const float* Wm  = (const float*)d_in[3];
  const float* bm  = (const float*)d_in[4];
  const float* Wc  = (const float*)d_in[5];
  const float* bc  = (const float*)d_in[6];
  const float* Wl1 = (const float*)d_in[7];
  const float* bl1 = (const float*)d_in[8];
  const float* Wr1 = (const float*)d_in[9];
  const float* Wl2 = (const float*)d_in[10];
  const float* bl2 = (const float*)d_in[11];
  const float* Wr2 = (const float*)d_in[12];
  const int* src = ei;
  const int* dst = ei + EE;

  char* w = (char*)d_ws;
  auto alloc = [&](size_t sz){ void* p = (void*)w; w += (sz + 255) & ~(size_t)255; return p; };
  unsigned short* mel_h = (unsigned short*)alloc((size_t)NN*HD*2);  // reused as y1 after GEMM2
  unsigned short* x     = (unsigned short*)alloc((size_t)NN*HD*2);
  unsigned short* z1    = (unsigned short*)alloc((size_t)NN*HD*2);
  int*   ssrc   = (int*)alloc((size_t)EE*4);
  int*   rank   = (int*)alloc((size_t)EE*4);
  int*   cnt    = (int*)alloc((size_t)NN*4);
  int*   offs   = (int*)alloc((size_t)NN*4);
  int*   blksum = (int*)alloc(4096);
  float* y2     = (float*)alloc((size_t)NN*4*4);
  float* r2     = (float*)alloc((size_t)NN*4*4);

  // --- CSR build: single atomic pass (hist+rank), scan, atomic-free place ---
  k_zero<<<(NN+255)/256, 256, 0, stream>>>(cnt, NN);
  k_histrank<<<(EE+255)/256, 256, 0, stream>>>(dst, cnt, rank, EE);
  int nblk = (NN + 1023) / 1024;  // 98
  k_scan1<<<nblk, 1024, 0, stream>>>(cnt, offs, blksum, NN);
  k_scan2<<<1, 128, 0, stream>>>(blksum, nblk);
  k_scan3<<<nblk, 1024, 0, stream>>>(offs, blksum, NN);
  k_place<<<(EE+255)/256, 256, 0, stream>>>(src, dst, offs, rank, ssrc, EE);

  int gmb = (NN + 127) / 128;     // 782 row tiles
  // mel_h = relu(mel @ Wm^T + bm)          (A fp32, B fp32)
  k_gemm<<<gmb, 256, 0, stream>>>(NN, mel, 1280, 1280, 1, nullptr, 0, 0, 0,
                                  Wm, 1280, nullptr, 0, bm, 1, mel_h, HD);
  // x = relu([clinical | mel_h] @ Wc^T + bc)   (seg0 fp32 K=64, seg1 bf16 K=128)
  k_gemm<<<gmb, 256, 0, stream>>>(NN, clinical, 64, 64, 1, mel_h, HD, HD, 0,
                                  Wc, 192, Wc + 64, 192, bc, 1, x, HD);
  // y1 = x @ Wl1^T   (into mel_h buffer — mel_h dead after GEMM2)
  unsigned short* y1 = mel_h;
  k_gemm<<<gmb, 256, 0, stream>>>(NN, x, HD, HD, 0, nullptr, 0, 0, 0,
                                  Wl1, HD, nullptr, 0, nullptr, 0, y1, HD);
  // z1 = x @ Wr1^T + bl1
  k_gemm<<<gmb, 256, 0, stream>>>(NN, x, HD, HD, 0, nullptr, 0, 0, 0,
                                  Wr1, HD, nullptr, 0, bl1, 0, z1, HD);

  // layer-1 aggregate + relu + fused layer-2 projections
  k_agg1<<<(NN+3)/4, 256, 0, stream>>>(offs, cnt, ssrc, y1, z1, Wl2, Wr2, bl2, y2, r2, NN);
  // layer-2 aggregate + fp32 output
  k_agg2<<<(NN+3)/4, 256, 0, stream>>>(offs, cnt, ssrc, y2, r2, (float*)d_out, NN);
}